// Round 1
// baseline (309.186 us; speedup 1.0000x reference)
//
#include <hip/hip_runtime.h>

// Problem dims (fixed by reference)
#define Bq 32
#define Sq 64
#define Iq 256
#define Hq 256
#define Oq 128
#define Fq 512          // Iq + Hq
#define WPB 8           // workgroups per batch
#define NT 512          // threads per workgroup

// R5: barrier-free h transport. The R2 loop body (fused pre+nsq, inv+tanhf
// in critical, f-update shadow) is FROZEN bit-for-bit -- R3/R4 proved that
// splitting nsq/inv out regresses (97 -> 129/122 us).
// Changes vs R2/R4 skeleton, all in the TRANSPORT layer:
//  (a) no per-step __syncthreads, no LDS h staging: each wave polls the full
//      256-slot h vector itself (4 x 8B tagged atomic loads per lane) and
//      redistributes in-register via 16 shfls. The all-to-all tag dependency
//      bounds inter-wave drift to <2 steps, so the 2-parity slots stay safe.
//  (b) x_0..x_63 all preloaded to LDS (exactly 64KB); no staging crew needed.
//  (c) f-update h-part reuses the shuffled registers (saves 4 ds_read_b128).
//  (d) epilogue reuses xall[0..255] as the h_fin staging buffer.
__global__ __launch_bounds__(NT, 2) void stpn_main(
    const float* __restrict__ x,     // (B,S,I)
    const float* __restrict__ w,     // (H,F)
    const float* __restrict__ wl,    // (H,F)
    const float* __restrict__ wgm,   // (H,F)
    const float* __restrict__ bias,  // (H)
    const float* __restrict__ ow,    // (O,H)
    const float* __restrict__ ob,    // (O)
    float* __restrict__ out,         // [tag(B*O) | h_fin(B*H) | f_fin(B*H*F)]
    unsigned long long* __restrict__ hb) // [2][B][H] (tag<<32|bits) slots
{
    const int blk   = blockIdx.x;
    const int b     = blk & 31;       // all 8 wgs of a batch -> same XCD
    const int chunk = blk >> 5;       // 0..7
    const int h0    = chunk * 32;
    const int tid   = threadIdx.x;
    const int lr    = tid & 15;       // lane within row
    const int r     = tid >> 4;       // row 0..31
    const int row   = h0 + r;
    const int ln    = tid & 63;       // lane within wave

    __shared__ float xall[Sq * Iq];   // 64 KB: x_0..x_63

    // Static params + fast-weight state in registers for all 64 steps.
    float fw[32], fl[32], fg[32], ff[32];
    const size_t rowoff = (size_t)row * Fq;
#pragma unroll
    for (int j = 0; j < 8; ++j) {
        const int c = 4 * lr + 64 * j;
        *(float4*)&fw[4*j] = *(const float4*)(w   + rowoff + c);
        *(float4*)&fl[4*j] = *(const float4*)(wl  + rowoff + c);
        *(float4*)&fg[4*j] = *(const float4*)(wgm + rowoff + c);
    }
#pragma unroll
    for (int j = 0; j < 32; ++j) ff[j] = 0.f;

    // Prologue x preload: 64*256/4 = 4096 float4 = 512 threads x 8.
    {
        const float4* xs = (const float4*)(x + (size_t)b * Sq * Iq);
        float4* xd = (float4*)xall;
#pragma unroll
        for (int k = 0; k < (Sq * Iq / 4) / NT; ++k)
            xd[tid + NT * k] = xs[tid + NT * k];
    }
    const float brow = bias[row];
    __syncthreads();                  // the ONLY wg barrier in the main loop

    for (int t = 0; t < Sq; ++t) {
        // ---- transport: poll h_{t-1} directly into this wave ----
        float hv0 = 0.f, hv1 = 0.f, hv2 = 0.f, hv3 = 0.f;
        if (t > 0) {
            const unsigned tt = (unsigned)t;
            unsigned long long* s0 =
                hb + (size_t)((t - 1) & 1) * Bq * Hq + (size_t)b * Hq + ln;
            unsigned long long v0, v1, v2, v3;
            do {
                v0 = __hip_atomic_load(s0,       __ATOMIC_RELAXED, __HIP_MEMORY_SCOPE_AGENT);
                v1 = __hip_atomic_load(s0 + 64,  __ATOMIC_RELAXED, __HIP_MEMORY_SCOPE_AGENT);
                v2 = __hip_atomic_load(s0 + 128, __ATOMIC_RELAXED, __HIP_MEMORY_SCOPE_AGENT);
                v3 = __hip_atomic_load(s0 + 192, __ATOMIC_RELAXED, __HIP_MEMORY_SCOPE_AGENT);
            } while (!((unsigned)(v0 >> 32) == tt && (unsigned)(v1 >> 32) == tt &&
                       (unsigned)(v2 >> 32) == tt && (unsigned)(v3 >> 32) == tt));
            hv0 = __uint_as_float((unsigned)(v0 & 0xffffffffu));
            hv1 = __uint_as_float((unsigned)(v1 & 0xffffffffu));
            hv2 = __uint_as_float((unsigned)(v2 & 0xffffffffu));
            hv3 = __uint_as_float((unsigned)(v3 & 0xffffffffu));
        }
        // redistribute: hp[jj][e] = h_{t-1}[4*lr + 64*jj + e]
        //   slot s = 4*lr + 64*jj + e lives in lane (4*lr+e), word jj.
        float hp[4][4];
        const int src = 4 * lr;
#pragma unroll
        for (int e = 0; e < 4; ++e) {
            hp[0][e] = __shfl(hv0, src + e, 64);
            hp[1][e] = __shfl(hv1, src + e, 64);
            hp[2][e] = __shfl(hv2, src + e, 64);
            hp[3][e] = __shfl(hv3, src + e, 64);
        }

        const float* xpart = xall + t * Iq;

        // ---- critical (FROZEN R2 body): fused pre+nsq -> butterflies ->
        //      inv -> tanh -> publish
        float pre = 0.f, nsq = 0.f;
#pragma unroll
        for (int j = 0; j < 4; ++j) {
            const float4 tv = *(const float4*)&xpart[4 * lr + 64 * j];
            float tw;
            tw = fw[4*j+0] + ff[4*j+0]; pre = fmaf(tv.x, tw, pre); nsq = fmaf(tw, tw, nsq);
            tw = fw[4*j+1] + ff[4*j+1]; pre = fmaf(tv.y, tw, pre); nsq = fmaf(tw, tw, nsq);
            tw = fw[4*j+2] + ff[4*j+2]; pre = fmaf(tv.z, tw, pre); nsq = fmaf(tw, tw, nsq);
            tw = fw[4*j+3] + ff[4*j+3]; pre = fmaf(tv.w, tw, pre); nsq = fmaf(tw, tw, nsq);
        }
#pragma unroll
        for (int j = 4; j < 8; ++j) {
            const int jj = j - 4;
            float tw;
            tw = fw[4*j+0] + ff[4*j+0]; pre = fmaf(hp[jj][0], tw, pre); nsq = fmaf(tw, tw, nsq);
            tw = fw[4*j+1] + ff[4*j+1]; pre = fmaf(hp[jj][1], tw, pre); nsq = fmaf(tw, tw, nsq);
            tw = fw[4*j+2] + ff[4*j+2]; pre = fmaf(hp[jj][2], tw, pre); nsq = fmaf(tw, tw, nsq);
            tw = fw[4*j+3] + ff[4*j+3]; pre = fmaf(hp[jj][3], tw, pre); nsq = fmaf(tw, tw, nsq);
        }
#pragma unroll
        for (int m = 1; m < 16; m <<= 1) {
            pre += __shfl_xor(pre, m, 16);
            nsq += __shfl_xor(nsq, m, 16);
        }
        const float inv = __fdividef(1.0f, sqrtf(nsq) + 1e-16f);
        const float hn  = tanhf(fmaf(pre, inv, brow));

        if (lr == 0) {
            const unsigned long long pk =
                ((unsigned long long)(unsigned)(t + 1) << 32) |
                (unsigned long long)__float_as_uint(hn);
            __hip_atomic_store(
                hb + (size_t)(t & 1) * Bq * Hq + (size_t)b * Hq + row, pk,
                __ATOMIC_RELAXED, __HIP_MEMORY_SCOPE_AGENT);
        }

        // ---- shadow: f update (h part from hp regs) ----
#pragma unroll
        for (int j = 0; j < 4; ++j) {
            const float4 tv = *(const float4*)&xpart[4 * lr + 64 * j];
            ff[4*j+0] = fmaf(fl[4*j+0], ff[4*j+0] * inv, fg[4*j+0] * (hn * tv.x));
            ff[4*j+1] = fmaf(fl[4*j+1], ff[4*j+1] * inv, fg[4*j+1] * (hn * tv.y));
            ff[4*j+2] = fmaf(fl[4*j+2], ff[4*j+2] * inv, fg[4*j+2] * (hn * tv.z));
            ff[4*j+3] = fmaf(fl[4*j+3], ff[4*j+3] * inv, fg[4*j+3] * (hn * tv.w));
        }
#pragma unroll
        for (int j = 4; j < 8; ++j) {
            const int jj = j - 4;
            ff[4*j+0] = fmaf(fl[4*j+0], ff[4*j+0] * inv, fg[4*j+0] * (hn * hp[jj][0]));
            ff[4*j+1] = fmaf(fl[4*j+1], ff[4*j+1] * inv, fg[4*j+1] * (hn * hp[jj][1]));
            ff[4*j+2] = fmaf(fl[4*j+2], ff[4*j+2] * inv, fg[4*j+2] * (hn * hp[jj][2]));
            ff[4*j+3] = fmaf(fl[4*j+3], ff[4*j+3] * inv, fg[4*j+3] * (hn * hp[jj][3]));
        }
    }

    // ---- f_fin: 16 lanes x float4 per row chunk ----
    float* fo = out + Bq * Oq + Bq * Hq + (size_t)b * Hq * Fq + rowoff;
#pragma unroll
    for (int j = 0; j < 8; ++j) {
        const int c = 4 * lr + 64 * j;
        *(float4*)(fo + c) = *(const float4*)&ff[4*j];
    }

    // ---- epilogue (chunk-0 wg per batch): h_fin + tag_space ----
    if (chunk == 0) {
        float* hbuf = xall;   // reuse step-0 region (disjoint from t=63 reads)
        if (tid < Hq) {
            unsigned long long* slot =
                hb + (size_t)1 * Bq * Hq + (size_t)b * Hq + tid;  // t=63 -> parity 1
            unsigned long long v;
            do {
                v = __hip_atomic_load(slot, __ATOMIC_RELAXED,
                                      __HIP_MEMORY_SCOPE_AGENT);
            } while ((unsigned)(v >> 32) != (unsigned)Sq);
            const float hv = __uint_as_float((unsigned)(v & 0xffffffffu));
            hbuf[tid] = hv;
            out[Bq * Oq + (size_t)b * Hq + tid] = hv;     // h_fin
        }
        __syncthreads();
        // 512 threads = 128 outputs x 4 lanes; lane l sums cols 16k+4l..+3.
        const int o = tid >> 2;
        const int l = tid & 3;
        const float* wr = ow + (size_t)o * Hq;
        float acc = 0.f;
#pragma unroll
        for (int k = 0; k < 16; ++k) {
            const int cc = 16 * k + 4 * l;
            const float4 w4 = *(const float4*)(wr + cc);
            const float4 h4 = *(const float4*)&hbuf[cc];
            acc += w4.x * h4.x + w4.y * h4.y + w4.z * h4.z + w4.w * h4.w;
        }
        acc += __shfl_xor(acc, 1, 4);
        acc += __shfl_xor(acc, 2, 4);
        if (l == 0) out[(size_t)b * Oq + o] = acc + ob[o];
    }
}

extern "C" void kernel_launch(void* const* d_in, const int* in_sizes, int n_in,
                              void* d_out, int out_size, void* d_ws, size_t ws_size,
                              hipStream_t stream)
{
    const float* x    = (const float*)d_in[0];
    const float* w    = (const float*)d_in[1];
    const float* wl   = (const float*)d_in[2];
    const float* wgm  = (const float*)d_in[3];
    const float* bias = (const float*)d_in[4];
    const float* ow   = (const float*)d_in[5];
    const float* ob   = (const float*)d_in[6];
    float* out = (float*)d_out;

    // Zero the (tag,val) h-exchange slots: 2 * B * H * 8 bytes.
    hipMemsetAsync(d_ws, 0, 2 * Bq * Hq * sizeof(unsigned long long), stream);

    stpn_main<<<Bq * WPB, NT, 0, stream>>>(x, w, wl, wgm, bias, ow, ob, out,
                                           (unsigned long long*)d_ws);
}

// Round 2
// 170.767 us; speedup vs baseline: 1.8106x; 1.8106x over previous
//
#include <hip/hip_runtime.h>

// Problem dims (fixed by reference)
#define Bq 32
#define Sq 64
#define Iq 256
#define Hq 256
#define Oq 128
#define Fq 512          // Iq + Hq
#define WPB 8           // workgroups per batch
#define NT 512          // threads per workgroup
#define PRE_S 62        // x steps preloaded in LDS: 62KB + 1KB hbuf + flag <= 64KB

// R6: wave0-consolidated transport. R2 loop body (fused pre+nsq, inv+tanhf
// in critical, f-update shadow) remains FROZEN bit-for-bit.
// R5 post-mortem: per-wave redundant atomic reads (64 waves x 256 slots)
// oversubscribe the L2 atomic pipes (atomics are per-lane, non-coalescing)
// -> 250us. Budget proven OK by R2: ONE reader per WG (2K lane-ops/step/batch).
// R6 keeps that budget but removes R2's two serial hops per step:
//  (a) no __syncthreads per step: wave0 spins the 256 tagged slots itself
//      (4 loads/lane; detection == data arrival), writes hbuf in LDS,
//      release-stores an LDS flag. Siblings spin the flag (same-address
//      ds_read broadcast, ~60cy hand-off vs ~200-300cy full barrier).
//  (b) x-part of pre/nsq hoisted BEFORE the transport wait (needs only the
//      locally-computed ff_t), overlapping FMA+LDS work with publish->detect.
//  (c) single-buffer hbuf is safe: wave0 passing spin(t) implies all waves
//      published t-1, which follows their last hbuf read. Shadow h-operands
//      therefore come from regs (hr[4]), never re-read from LDS.
//  (d) xall covers 62 steps; t=62,63 read x directly from global (L2-hot),
//      issued pre-spin so the latency is hidden.
__global__ __launch_bounds__(NT, 2) void stpn_main(
    const float* __restrict__ x,     // (B,S,I)
    const float* __restrict__ w,     // (H,F)
    const float* __restrict__ wl,    // (H,F)
    const float* __restrict__ wgm,   // (H,F)
    const float* __restrict__ bias,  // (H)
    const float* __restrict__ ow,    // (O,H)
    const float* __restrict__ ob,    // (O)
    float* __restrict__ out,         // [tag(B*O) | h_fin(B*H) | f_fin(B*H*F)]
    unsigned long long* __restrict__ hb) // [2][B][H] (tag<<32|bits) slots
{
    const int blk   = blockIdx.x;
    const int b     = blk & 31;       // 8 wgs of a batch land round-robin
    const int chunk = blk >> 5;       // 0..7
    const int h0    = chunk * 32;
    const int tid   = threadIdx.x;
    const int lr    = tid & 15;       // lane within row
    const int r     = tid >> 4;       // row 0..31
    const int row   = h0 + r;
    const int ln    = tid & 63;       // lane within wave
    const int wv    = tid >> 6;       // wave id within wg

    __shared__ float xall[PRE_S * Iq];   // 62 KB
    __shared__ float hbuf[Hq];           // 1 KB: h_{t-1} broadcast buffer
    __shared__ unsigned hflag;           // step tag of hbuf contents

    // Static params + fast-weight state in registers for all 64 steps.
    float fw[32], fl[32], fg[32], ff[32];
    const size_t rowoff = (size_t)row * Fq;
#pragma unroll
    for (int j = 0; j < 8; ++j) {
        const int c = 4 * lr + 64 * j;
        *(float4*)&fw[4*j] = *(const float4*)(w   + rowoff + c);
        *(float4*)&fl[4*j] = *(const float4*)(wl  + rowoff + c);
        *(float4*)&fg[4*j] = *(const float4*)(wgm + rowoff + c);
    }
#pragma unroll
    for (int j = 0; j < 32; ++j) ff[j] = 0.f;

    // Prologue x preload: 62*256/4 = 3968 float4 = 512*7 + 384.
    {
        const float4* xs = (const float4*)(x + (size_t)b * Sq * Iq);
        float4* xd = (float4*)xall;
#pragma unroll
        for (int k = 0; k < 7; ++k)
            xd[tid + NT * k] = xs[tid + NT * k];
        if (tid < 384) xd[tid + 3584] = xs[tid + 3584];
    }
    if (tid < Hq) hbuf[tid] = 0.f;    // t=0 reads h = 0
    if (tid == 0) hflag = 0u;
    const float brow = bias[row];
    const float* xb = x + (size_t)b * Sq * Iq;
    __syncthreads();                  // covers preload + hbuf/hflag init

    for (int t = 0; t < Sq; ++t) {
        // ---- x-part of fused pre+nsq (js 0..3): no transport dependency ----
        float pre = 0.f, nsq = 0.f;
        if (t < PRE_S) {
            const float* xpart = xall + t * Iq;
#pragma unroll
            for (int j = 0; j < 4; ++j) {
                const float4 tv = *(const float4*)&xpart[4 * lr + 64 * j];
                float tw;
                tw = fw[4*j+0] + ff[4*j+0]; pre = fmaf(tv.x, tw, pre); nsq = fmaf(tw, tw, nsq);
                tw = fw[4*j+1] + ff[4*j+1]; pre = fmaf(tv.y, tw, pre); nsq = fmaf(tw, tw, nsq);
                tw = fw[4*j+2] + ff[4*j+2]; pre = fmaf(tv.z, tw, pre); nsq = fmaf(tw, tw, nsq);
                tw = fw[4*j+3] + ff[4*j+3]; pre = fmaf(tv.w, tw, pre); nsq = fmaf(tw, tw, nsq);
            }
        } else {
            const float* xpart = xb + (size_t)t * Iq;
#pragma unroll
            for (int j = 0; j < 4; ++j) {
                const float4 tv = *(const float4*)&xpart[4 * lr + 64 * j];
                float tw;
                tw = fw[4*j+0] + ff[4*j+0]; pre = fmaf(tv.x, tw, pre); nsq = fmaf(tw, tw, nsq);
                tw = fw[4*j+1] + ff[4*j+1]; pre = fmaf(tv.y, tw, pre); nsq = fmaf(tw, tw, nsq);
                tw = fw[4*j+2] + ff[4*j+2]; pre = fmaf(tv.z, tw, pre); nsq = fmaf(tw, tw, nsq);
                tw = fw[4*j+3] + ff[4*j+3]; pre = fmaf(tv.w, tw, pre); nsq = fmaf(tw, tw, nsq);
            }
        }

        // ---- transport: wave0 fetches h_{t-1}, siblings wait on LDS flag ----
        if (t > 0) {
            const unsigned tt = (unsigned)t;
            if (wv == 0) {
                unsigned long long* s0 =
                    hb + (size_t)((t - 1) & 1) * Bq * Hq + (size_t)b * Hq + ln;
                unsigned long long v0, v1, v2, v3;
                do {
                    v0 = __hip_atomic_load(s0,       __ATOMIC_RELAXED, __HIP_MEMORY_SCOPE_AGENT);
                    v1 = __hip_atomic_load(s0 + 64,  __ATOMIC_RELAXED, __HIP_MEMORY_SCOPE_AGENT);
                    v2 = __hip_atomic_load(s0 + 128, __ATOMIC_RELAXED, __HIP_MEMORY_SCOPE_AGENT);
                    v3 = __hip_atomic_load(s0 + 192, __ATOMIC_RELAXED, __HIP_MEMORY_SCOPE_AGENT);
                } while (!((unsigned)(v0 >> 32) == tt && (unsigned)(v1 >> 32) == tt &&
                           (unsigned)(v2 >> 32) == tt && (unsigned)(v3 >> 32) == tt));
                hbuf[ln      ] = __uint_as_float((unsigned)(v0 & 0xffffffffu));
                hbuf[ln + 64 ] = __uint_as_float((unsigned)(v1 & 0xffffffffu));
                hbuf[ln + 128] = __uint_as_float((unsigned)(v2 & 0xffffffffu));
                hbuf[ln + 192] = __uint_as_float((unsigned)(v3 & 0xffffffffu));
                if (ln == 0)
                    __hip_atomic_store(&hflag, tt, __ATOMIC_RELEASE,
                                       __HIP_MEMORY_SCOPE_WORKGROUP);
            } else {
                while (__hip_atomic_load(&hflag, __ATOMIC_ACQUIRE,
                                         __HIP_MEMORY_SCOPE_WORKGROUP) != tt) {}
            }
        }

        // ---- h-part (js 4..7); keep operands in regs for the shadow ----
        float4 hr[4];
#pragma unroll
        for (int jj = 0; jj < 4; ++jj)
            hr[jj] = *(const float4*)&hbuf[4 * lr + 64 * jj];
#pragma unroll
        for (int j = 4; j < 8; ++j) {
            const int jj = j - 4;
            float tw;
            tw = fw[4*j+0] + ff[4*j+0]; pre = fmaf(hr[jj].x, tw, pre); nsq = fmaf(tw, tw, nsq);
            tw = fw[4*j+1] + ff[4*j+1]; pre = fmaf(hr[jj].y, tw, pre); nsq = fmaf(tw, tw, nsq);
            tw = fw[4*j+2] + ff[4*j+2]; pre = fmaf(hr[jj].z, tw, pre); nsq = fmaf(tw, tw, nsq);
            tw = fw[4*j+3] + ff[4*j+3]; pre = fmaf(hr[jj].w, tw, pre); nsq = fmaf(tw, tw, nsq);
        }
#pragma unroll
        for (int m = 1; m < 16; m <<= 1) {
            pre += __shfl_xor(pre, m, 16);
            nsq += __shfl_xor(nsq, m, 16);
        }
        const float inv = __fdividef(1.0f, sqrtf(nsq) + 1e-16f);
        const float hn  = tanhf(fmaf(pre, inv, brow));

        if (lr == 0) {
            const unsigned long long pk =
                ((unsigned long long)(unsigned)(t + 1) << 32) |
                (unsigned long long)__float_as_uint(hn);
            __hip_atomic_store(
                hb + (size_t)(t & 1) * Bq * Hq + (size_t)b * Hq + row, pk,
                __ATOMIC_RELAXED, __HIP_MEMORY_SCOPE_AGENT);
        }

        // ---- shadow: f update (x re-read; h from hr regs) ----
        if (t < PRE_S) {
            const float* xpart = xall + t * Iq;
#pragma unroll
            for (int j = 0; j < 4; ++j) {
                const float4 tv = *(const float4*)&xpart[4 * lr + 64 * j];
                ff[4*j+0] = fmaf(fl[4*j+0], ff[4*j+0] * inv, fg[4*j+0] * (hn * tv.x));
                ff[4*j+1] = fmaf(fl[4*j+1], ff[4*j+1] * inv, fg[4*j+1] * (hn * tv.y));
                ff[4*j+2] = fmaf(fl[4*j+2], ff[4*j+2] * inv, fg[4*j+2] * (hn * tv.z));
                ff[4*j+3] = fmaf(fl[4*j+3], ff[4*j+3] * inv, fg[4*j+3] * (hn * tv.w));
            }
        } else {
            const float* xpart = xb + (size_t)t * Iq;
#pragma unroll
            for (int j = 0; j < 4; ++j) {
                const float4 tv = *(const float4*)&xpart[4 * lr + 64 * j];
                ff[4*j+0] = fmaf(fl[4*j+0], ff[4*j+0] * inv, fg[4*j+0] * (hn * tv.x));
                ff[4*j+1] = fmaf(fl[4*j+1], ff[4*j+1] * inv, fg[4*j+1] * (hn * tv.y));
                ff[4*j+2] = fmaf(fl[4*j+2], ff[4*j+2] * inv, fg[4*j+2] * (hn * tv.z));
                ff[4*j+3] = fmaf(fl[4*j+3], ff[4*j+3] * inv, fg[4*j+3] * (hn * tv.w));
            }
        }
#pragma unroll
        for (int j = 4; j < 8; ++j) {
            const int jj = j - 4;
            ff[4*j+0] = fmaf(fl[4*j+0], ff[4*j+0] * inv, fg[4*j+0] * (hn * hr[jj].x));
            ff[4*j+1] = fmaf(fl[4*j+1], ff[4*j+1] * inv, fg[4*j+1] * (hn * hr[jj].y));
            ff[4*j+2] = fmaf(fl[4*j+2], ff[4*j+2] * inv, fg[4*j+2] * (hn * hr[jj].z));
            ff[4*j+3] = fmaf(fl[4*j+3], ff[4*j+3] * inv, fg[4*j+3] * (hn * hr[jj].w));
        }
    }

    // ---- f_fin: 16 lanes x float4 per row chunk ----
    float* fo = out + Bq * Oq + Bq * Hq + (size_t)b * Hq * Fq + rowoff;
#pragma unroll
    for (int j = 0; j < 8; ++j) {
        const int c = 4 * lr + 64 * j;
        *(float4*)(fo + c) = *(const float4*)&ff[4*j];
    }

    // ---- epilogue (chunk-0 wg per batch): h_fin + tag_space ----
    if (chunk == 0) {
        __syncthreads();   // all waves past their last hbuf read before reuse
        if (tid < Hq) {
            unsigned long long* slot =
                hb + (size_t)1 * Bq * Hq + (size_t)b * Hq + tid;  // t=63 -> parity 1
            unsigned long long v;
            do {
                v = __hip_atomic_load(slot, __ATOMIC_RELAXED,
                                      __HIP_MEMORY_SCOPE_AGENT);
            } while ((unsigned)(v >> 32) != (unsigned)Sq);
            const float hv = __uint_as_float((unsigned)(v & 0xffffffffu));
            hbuf[tid] = hv;
            out[Bq * Oq + (size_t)b * Hq + tid] = hv;     // h_fin
        }
        __syncthreads();
        // 512 threads = 128 outputs x 4 lanes; lane l sums cols 16k+4l..+3.
        const int o = tid >> 2;
        const int l = tid & 3;
        const float* wr = ow + (size_t)o * Hq;
        float acc = 0.f;
#pragma unroll
        for (int k = 0; k < 16; ++k) {
            const int cc = 16 * k + 4 * l;
            const float4 w4 = *(const float4*)(wr + cc);
            const float4 h4 = *(const float4*)&hbuf[cc];
            acc += w4.x * h4.x + w4.y * h4.y + w4.z * h4.z + w4.w * h4.w;
        }
        acc += __shfl_xor(acc, 1, 4);
        acc += __shfl_xor(acc, 2, 4);
        if (l == 0) out[(size_t)b * Oq + o] = acc + ob[o];
    }
}

extern "C" void kernel_launch(void* const* d_in, const int* in_sizes, int n_in,
                              void* d_out, int out_size, void* d_ws, size_t ws_size,
                              hipStream_t stream)
{
    const float* x    = (const float*)d_in[0];
    const float* w    = (const float*)d_in[1];
    const float* wl   = (const float*)d_in[2];
    const float* wgm  = (const float*)d_in[3];
    const float* bias = (const float*)d_in[4];
    const float* ow   = (const float*)d_in[5];
    const float* ob   = (const float*)d_in[6];
    float* out = (float*)d_out;

    // Zero the (tag,val) h-exchange slots: 2 * B * H * 8 bytes = 128 KB.
    hipMemsetAsync(d_ws, 0, 2 * Bq * Hq * sizeof(unsigned long long), stream);

    stpn_main<<<Bq * WPB, NT, 0, stream>>>(x, w, wl, wgm, bias, ow, ob, out,
                                           (unsigned long long*)d_ws);
}

// Round 3
// 156.201 us; speedup vs baseline: 1.9794x; 1.0933x over previous
//
#include <hip/hip_runtime.h>

// Problem dims (fixed by reference)
#define Bq 32
#define Sq 64
#define Iq 256
#define Hq 256
#define Oq 128
#define Fq 512          // Iq + Hq
#define WPB 8           // workgroups per batch
#define NT 512          // threads per workgroup
#define PRE_S 62        // x steps preloaded in LDS: 62KB + 1KB hbuf + flag <= 64KB

// R7: resource-allocation fix + serial-chain cut. Transport layer is R6's
// (wave0 polls tagged slots, LDS flag hand-off) -- proven equal to R2's
// barrier transport (101 vs 102us), so the bottleneck is elsewhere:
//  (a) __launch_bounds__(NT, 1): the old ",2" capped the allocator at 128
//      arch-VGPRs while per-thread persistent state alone is 128 floats
//      (fw/fl/fg/ff) -> VGPR_Count=104 proved the state was bouncing through
//      AGPRs (accvgpr moves every access, ~96 extra VALU ops/step) and ",2"
//      permitted 2-WG/CU packing that convoys the all-to-all recurrence.
//      Grid is 256 WGs on 256 CUs: we want exactly 1 WG/CU, 256 VGPRs.
//  (b) tanhf (branchy libm + precise divide, on the 64x-serial chain)
//      replaced by tanh(z) = 1 - 2/(exp(2z)+1) via __expf + __fdividef
//      (~5 ops; +-2-3ulp; saturates cleanly to +-1 for |z| large).
// Everything else is bit-frozen R6: fused pre+nsq, butterflies, inv in
// critical, f-update shadow, wave0 transport, PRE_S=62 split.
__global__ __launch_bounds__(NT, 1) void stpn_main(
    const float* __restrict__ x,     // (B,S,I)
    const float* __restrict__ w,     // (H,F)
    const float* __restrict__ wl,    // (H,F)
    const float* __restrict__ wgm,   // (H,F)
    const float* __restrict__ bias,  // (H)
    const float* __restrict__ ow,    // (O,H)
    const float* __restrict__ ob,    // (O)
    float* __restrict__ out,         // [tag(B*O) | h_fin(B*H) | f_fin(B*H*F)]
    unsigned long long* __restrict__ hb) // [2][B][H] (tag<<32|bits) slots
{
    const int blk   = blockIdx.x;
    const int b     = blk & 31;       // 8 wgs of a batch land round-robin
    const int chunk = blk >> 5;       // 0..7
    const int h0    = chunk * 32;
    const int tid   = threadIdx.x;
    const int lr    = tid & 15;       // lane within row
    const int r     = tid >> 4;       // row 0..31
    const int row   = h0 + r;
    const int ln    = tid & 63;       // lane within wave
    const int wv    = tid >> 6;       // wave id within wg

    __shared__ float xall[PRE_S * Iq];   // 62 KB
    __shared__ float hbuf[Hq];           // 1 KB: h_{t-1} broadcast buffer
    __shared__ unsigned hflag;           // step tag of hbuf contents

    // Static params + fast-weight state in registers for all 64 steps.
    float fw[32], fl[32], fg[32], ff[32];
    const size_t rowoff = (size_t)row * Fq;
#pragma unroll
    for (int j = 0; j < 8; ++j) {
        const int c = 4 * lr + 64 * j;
        *(float4*)&fw[4*j] = *(const float4*)(w   + rowoff + c);
        *(float4*)&fl[4*j] = *(const float4*)(wl  + rowoff + c);
        *(float4*)&fg[4*j] = *(const float4*)(wgm + rowoff + c);
    }
#pragma unroll
    for (int j = 0; j < 32; ++j) ff[j] = 0.f;

    // Prologue x preload: 62*256/4 = 3968 float4 = 512*7 + 384.
    {
        const float4* xs = (const float4*)(x + (size_t)b * Sq * Iq);
        float4* xd = (float4*)xall;
#pragma unroll
        for (int k = 0; k < 7; ++k)
            xd[tid + NT * k] = xs[tid + NT * k];
        if (tid < 384) xd[tid + 3584] = xs[tid + 3584];
    }
    if (tid < Hq) hbuf[tid] = 0.f;    // t=0 reads h = 0
    if (tid == 0) hflag = 0u;
    const float brow = bias[row];
    const float* xb = x + (size_t)b * Sq * Iq;
    __syncthreads();                  // covers preload + hbuf/hflag init

    for (int t = 0; t < Sq; ++t) {
        // ---- x-part of fused pre+nsq (js 0..3): no transport dependency ----
        float pre = 0.f, nsq = 0.f;
        if (t < PRE_S) {
            const float* xpart = xall + t * Iq;
#pragma unroll
            for (int j = 0; j < 4; ++j) {
                const float4 tv = *(const float4*)&xpart[4 * lr + 64 * j];
                float tw;
                tw = fw[4*j+0] + ff[4*j+0]; pre = fmaf(tv.x, tw, pre); nsq = fmaf(tw, tw, nsq);
                tw = fw[4*j+1] + ff[4*j+1]; pre = fmaf(tv.y, tw, pre); nsq = fmaf(tw, tw, nsq);
                tw = fw[4*j+2] + ff[4*j+2]; pre = fmaf(tv.z, tw, pre); nsq = fmaf(tw, tw, nsq);
                tw = fw[4*j+3] + ff[4*j+3]; pre = fmaf(tv.w, tw, pre); nsq = fmaf(tw, tw, nsq);
            }
        } else {
            const float* xpart = xb + (size_t)t * Iq;
#pragma unroll
            for (int j = 0; j < 4; ++j) {
                const float4 tv = *(const float4*)&xpart[4 * lr + 64 * j];
                float tw;
                tw = fw[4*j+0] + ff[4*j+0]; pre = fmaf(tv.x, tw, pre); nsq = fmaf(tw, tw, nsq);
                tw = fw[4*j+1] + ff[4*j+1]; pre = fmaf(tv.y, tw, pre); nsq = fmaf(tw, tw, nsq);
                tw = fw[4*j+2] + ff[4*j+2]; pre = fmaf(tv.z, tw, pre); nsq = fmaf(tw, tw, nsq);
                tw = fw[4*j+3] + ff[4*j+3]; pre = fmaf(tv.w, tw, pre); nsq = fmaf(tw, tw, nsq);
            }
        }

        // ---- transport: wave0 fetches h_{t-1}, siblings wait on LDS flag ----
        if (t > 0) {
            const unsigned tt = (unsigned)t;
            if (wv == 0) {
                unsigned long long* s0 =
                    hb + (size_t)((t - 1) & 1) * Bq * Hq + (size_t)b * Hq + ln;
                unsigned long long v0, v1, v2, v3;
                do {
                    v0 = __hip_atomic_load(s0,       __ATOMIC_RELAXED, __HIP_MEMORY_SCOPE_AGENT);
                    v1 = __hip_atomic_load(s0 + 64,  __ATOMIC_RELAXED, __HIP_MEMORY_SCOPE_AGENT);
                    v2 = __hip_atomic_load(s0 + 128, __ATOMIC_RELAXED, __HIP_MEMORY_SCOPE_AGENT);
                    v3 = __hip_atomic_load(s0 + 192, __ATOMIC_RELAXED, __HIP_MEMORY_SCOPE_AGENT);
                } while (!((unsigned)(v0 >> 32) == tt && (unsigned)(v1 >> 32) == tt &&
                           (unsigned)(v2 >> 32) == tt && (unsigned)(v3 >> 32) == tt));
                hbuf[ln      ] = __uint_as_float((unsigned)(v0 & 0xffffffffu));
                hbuf[ln + 64 ] = __uint_as_float((unsigned)(v1 & 0xffffffffu));
                hbuf[ln + 128] = __uint_as_float((unsigned)(v2 & 0xffffffffu));
                hbuf[ln + 192] = __uint_as_float((unsigned)(v3 & 0xffffffffu));
                if (ln == 0)
                    __hip_atomic_store(&hflag, tt, __ATOMIC_RELEASE,
                                       __HIP_MEMORY_SCOPE_WORKGROUP);
            } else {
                while (__hip_atomic_load(&hflag, __ATOMIC_ACQUIRE,
                                         __HIP_MEMORY_SCOPE_WORKGROUP) != tt) {}
            }
        }

        // ---- h-part (js 4..7); keep operands in regs for the shadow ----
        float4 hr[4];
#pragma unroll
        for (int jj = 0; jj < 4; ++jj)
            hr[jj] = *(const float4*)&hbuf[4 * lr + 64 * jj];
#pragma unroll
        for (int j = 4; j < 8; ++j) {
            const int jj = j - 4;
            float tw;
            tw = fw[4*j+0] + ff[4*j+0]; pre = fmaf(hr[jj].x, tw, pre); nsq = fmaf(tw, tw, nsq);
            tw = fw[4*j+1] + ff[4*j+1]; pre = fmaf(hr[jj].y, tw, pre); nsq = fmaf(tw, tw, nsq);
            tw = fw[4*j+2] + ff[4*j+2]; pre = fmaf(hr[jj].z, tw, pre); nsq = fmaf(tw, tw, nsq);
            tw = fw[4*j+3] + ff[4*j+3]; pre = fmaf(hr[jj].w, tw, pre); nsq = fmaf(tw, tw, nsq);
        }
#pragma unroll
        for (int m = 1; m < 16; m <<= 1) {
            pre += __shfl_xor(pre, m, 16);
            nsq += __shfl_xor(nsq, m, 16);
        }
        const float inv = __fdividef(1.0f, sqrtf(nsq) + 1e-16f);
        // tanh(z) = 1 - 2/(exp(2z)+1); saturates cleanly to +-1.
        const float z   = fmaf(pre, inv, brow);
        const float e2  = __expf(2.0f * z);
        const float hn  = 1.0f - __fdividef(2.0f, e2 + 1.0f);

        if (lr == 0) {
            const unsigned long long pk =
                ((unsigned long long)(unsigned)(t + 1) << 32) |
                (unsigned long long)__float_as_uint(hn);
            __hip_atomic_store(
                hb + (size_t)(t & 1) * Bq * Hq + (size_t)b * Hq + row, pk,
                __ATOMIC_RELAXED, __HIP_MEMORY_SCOPE_AGENT);
        }

        // ---- shadow: f update (x re-read; h from hr regs) ----
        if (t < PRE_S) {
            const float* xpart = xall + t * Iq;
#pragma unroll
            for (int j = 0; j < 4; ++j) {
                const float4 tv = *(const float4*)&xpart[4 * lr + 64 * j];
                ff[4*j+0] = fmaf(fl[4*j+0], ff[4*j+0] * inv, fg[4*j+0] * (hn * tv.x));
                ff[4*j+1] = fmaf(fl[4*j+1], ff[4*j+1] * inv, fg[4*j+1] * (hn * tv.y));
                ff[4*j+2] = fmaf(fl[4*j+2], ff[4*j+2] * inv, fg[4*j+2] * (hn * tv.z));
                ff[4*j+3] = fmaf(fl[4*j+3], ff[4*j+3] * inv, fg[4*j+3] * (hn * tv.w));
            }
        } else {
            const float* xpart = xb + (size_t)t * Iq;
#pragma unroll
            for (int j = 0; j < 4; ++j) {
                const float4 tv = *(const float4*)&xpart[4 * lr + 64 * j];
                ff[4*j+0] = fmaf(fl[4*j+0], ff[4*j+0] * inv, fg[4*j+0] * (hn * tv.x));
                ff[4*j+1] = fmaf(fl[4*j+1], ff[4*j+1] * inv, fg[4*j+1] * (hn * tv.y));
                ff[4*j+2] = fmaf(fl[4*j+2], ff[4*j+2] * inv, fg[4*j+2] * (hn * tv.z));
                ff[4*j+3] = fmaf(fl[4*j+3], ff[4*j+3] * inv, fg[4*j+3] * (hn * tv.w));
            }
        }
#pragma unroll
        for (int j = 4; j < 8; ++j) {
            const int jj = j - 4;
            ff[4*j+0] = fmaf(fl[4*j+0], ff[4*j+0] * inv, fg[4*j+0] * (hn * hr[jj].x));
            ff[4*j+1] = fmaf(fl[4*j+1], ff[4*j+1] * inv, fg[4*j+1] * (hn * hr[jj].y));
            ff[4*j+2] = fmaf(fl[4*j+2], ff[4*j+2] * inv, fg[4*j+2] * (hn * hr[jj].z));
            ff[4*j+3] = fmaf(fl[4*j+3], ff[4*j+3] * inv, fg[4*j+3] * (hn * hr[jj].w));
        }
    }

    // ---- f_fin: 16 lanes x float4 per row chunk ----
    float* fo = out + Bq * Oq + Bq * Hq + (size_t)b * Hq * Fq + rowoff;
#pragma unroll
    for (int j = 0; j < 8; ++j) {
        const int c = 4 * lr + 64 * j;
        *(float4*)(fo + c) = *(const float4*)&ff[4*j];
    }

    // ---- epilogue (chunk-0 wg per batch): h_fin + tag_space ----
    if (chunk == 0) {
        __syncthreads();   // all waves past their last hbuf read before reuse
        if (tid < Hq) {
            unsigned long long* slot =
                hb + (size_t)1 * Bq * Hq + (size_t)b * Hq + tid;  // t=63 -> parity 1
            unsigned long long v;
            do {
                v = __hip_atomic_load(slot, __ATOMIC_RELAXED,
                                      __HIP_MEMORY_SCOPE_AGENT);
            } while ((unsigned)(v >> 32) != (unsigned)Sq);
            const float hv = __uint_as_float((unsigned)(v & 0xffffffffu));
            hbuf[tid] = hv;
            out[Bq * Oq + (size_t)b * Hq + tid] = hv;     // h_fin
        }
        __syncthreads();
        // 512 threads = 128 outputs x 4 lanes; lane l sums cols 16k+4l..+3.
        const int o = tid >> 2;
        const int l = tid & 3;
        const float* wr = ow + (size_t)o * Hq;
        float acc = 0.f;
#pragma unroll
        for (int k = 0; k < 16; ++k) {
            const int cc = 16 * k + 4 * l;
            const float4 w4 = *(const float4*)(wr + cc);
            const float4 h4 = *(const float4*)&hbuf[cc];
            acc += w4.x * h4.x + w4.y * h4.y + w4.z * h4.z + w4.w * h4.w;
        }
        acc += __shfl_xor(acc, 1, 4);
        acc += __shfl_xor(acc, 2, 4);
        if (l == 0) out[(size_t)b * Oq + o] = acc + ob[o];
    }
}

extern "C" void kernel_launch(void* const* d_in, const int* in_sizes, int n_in,
                              void* d_out, int out_size, void* d_ws, size_t ws_size,
                              hipStream_t stream)
{
    const float* x    = (const float*)d_in[0];
    const float* w    = (const float*)d_in[1];
    const float* wl   = (const float*)d_in[2];
    const float* wgm  = (const float*)d_in[3];
    const float* bias = (const float*)d_in[4];
    const float* ow   = (const float*)d_in[5];
    const float* ob   = (const float*)d_in[6];
    float* out = (float*)d_out;

    // Zero the (tag,val) h-exchange slots: 2 * B * H * 8 bytes = 128 KB.
    hipMemsetAsync(d_ws, 0, 2 * Bq * Hq * sizeof(unsigned long long), stream);

    stpn_main<<<Bq * WPB, NT, 0, stream>>>(x, w, wl, wgm, bias, ow, ob, out,
                                           (unsigned long long*)d_ws);
}